// Round 11
// baseline (455.449 us; speedup 1.0000x reference)
//
#include <hip/hip_runtime.h>
#include <hip/hip_fp16.h>

// Topology encoder: 2-layer GCN (N=100k nodes, E=3.2M edges) + max/mean pool
// over B=64 graphs + 2-layer MLP. fp32 in/out; node features stored fp16 in
// TWO PLANES of N x 16 (3.2 MB each -> L2-resident per XCD during gathers),
// PRE-SCALED by dinv so the gather needs no per-edge dinv load:
//   out[d] = relu(bias + dinv[d] * (sum_{s in N(d)} hs[s] + hs[d])),
//   hs[x] = h[x] * dinv[x]   (scale applied in k_xw1 / k_gemm2 at write).
//
// CSR-by-dst built per call with ZERO global atomics (histB/rowscan/bscan/
// bin/place2). Gather: one kernel, both planes (plane = blockIdx&7 quadrant,
// XCD round-robin pinning); 8 threads per (node,plane), each owning a
// contiguous 1/8 slice of the edge list and the full 16-feat plane row.

#define F 32
#define POOLD 64
#define BKT 512           // nodes per bucket (log2 = 9); place2 blockDim == BKT
#define BKTL2 9
#define EPB 8192          // edges per k_histB/k_bin block
#define MAXBUCK 256       // supports N <= 131072

typedef __attribute__((ext_vector_type(8))) _Float16 half8;

// ---- per-block LDS bucket histogram; direct store to bcnt[b][blk] ----
__global__ void k_histB(const int* __restrict__ ei, int* __restrict__ bcnt,
                        int e, int nbuck, int nblk) {
    __shared__ int h[MAXBUCK];
    for (int b = threadIdx.x; b < nbuck; b += 256) h[b] = 0;
    __syncthreads();
    int base = blockIdx.x * EPB;
#pragma unroll
    for (int k = 0; k < EPB / 1024; ++k) {
        int i = base + (k * 256 + threadIdx.x) * 4;
        if (i + 4 <= e) {
            int4 d4 = *reinterpret_cast<const int4*>(ei + e + i);
            atomicAdd(&h[d4.x >> BKTL2], 1);
            atomicAdd(&h[d4.y >> BKTL2], 1);
            atomicAdd(&h[d4.z >> BKTL2], 1);
            atomicAdd(&h[d4.w >> BKTL2], 1);
        } else {
            for (int j = i; j < e && j < i + 4; ++j)
                atomicAdd(&h[ei[e + j] >> BKTL2], 1);
        }
    }
    __syncthreads();
    for (int b = threadIdx.x; b < nbuck; b += 256)
        bcnt[b * nblk + blockIdx.x] = h[b];
}

// ---- per bucket: exclusive scan of bcnt row (in place) + row total ----
__global__ void k_rowscan(int* __restrict__ bcnt, int* __restrict__ tot, int nblk) {
    __shared__ int lds[256];
    int* row = bcnt + (size_t)blockIdx.x * nblk;
    int t = threadIdx.x;
    int running = 0;
    for (int chunk = 0; chunk < nblk; chunk += 256) {
        int idx = chunk + t;
        int v = (idx < nblk) ? row[idx] : 0;
        lds[t] = v;
        __syncthreads();
        int val = v;
        for (int off = 1; off < 256; off <<= 1) {
            int other = (t >= off) ? lds[t - off] : 0;
            __syncthreads();
            val += other;
            lds[t] = val;
            __syncthreads();
        }
        if (idx < nblk) row[idx] = running + val - v;  // exclusive
        running += lds[255];
        __syncthreads();
    }
    if (t == 0) tot[blockIdx.x] = running;
}

// ---- single block: scan bucket totals -> bstart (nbuck <= 256) ----
__global__ void k_bscan(const int* __restrict__ tot, int* __restrict__ bstart,
                        int nbuck, int e) {
    __shared__ int lds[256];
    int t = threadIdx.x;
    int v = (t < nbuck) ? tot[t] : 0;
    lds[t] = v;
    __syncthreads();
    int val = v;
    for (int off = 1; off < 256; off <<= 1) {
        int other = (t >= off) ? lds[t - off] : 0;
        __syncthreads();
        val += other;
        lds[t] = val;
        __syncthreads();
    }
    if (t < nbuck) bstart[t] = val - v;  // exclusive
    if (t == 0) bstart[nbuck] = e;
}

// ---- partition edges into private per-(bucket,block) runs; LDS cursors ----
__global__ void k_bin(const int* __restrict__ ei, const int* __restrict__ bstart,
                      const int* __restrict__ bcnt, int* __restrict__ packed,
                      int e, int nbuck, int nblk) {
    __shared__ int cur[MAXBUCK];
    for (int b = threadIdx.x; b < nbuck; b += 256)
        cur[b] = bstart[b] + bcnt[b * nblk + blockIdx.x];
    __syncthreads();
    int base = blockIdx.x * EPB;
#pragma unroll
    for (int k = 0; k < EPB / 1024; ++k) {
        int i = base + (k * 256 + threadIdx.x) * 4;
        if (i + 4 <= e) {
            int4 s4 = *reinterpret_cast<const int4*>(ei + i);
            int4 d4 = *reinterpret_cast<const int4*>(ei + e + i);
            int p0 = atomicAdd(&cur[d4.x >> BKTL2], 1);
            int p1 = atomicAdd(&cur[d4.y >> BKTL2], 1);
            int p2 = atomicAdd(&cur[d4.z >> BKTL2], 1);
            int p3 = atomicAdd(&cur[d4.w >> BKTL2], 1);
            packed[p0] = (s4.x << BKTL2) | (d4.x & (BKT - 1));
            packed[p1] = (s4.y << BKTL2) | (d4.y & (BKT - 1));
            packed[p2] = (s4.z << BKTL2) | (d4.z & (BKT - 1));
            packed[p3] = (s4.w << BKTL2) | (d4.w & (BKT - 1));
        } else {
            for (int j = i; j < e && j < i + 4; ++j) {
                int s = ei[j], d = ei[e + j];
                int p = atomicAdd(&cur[d >> BKTL2], 1);
                packed[p] = (s << BKTL2) | (d & (BKT - 1));
            }
        }
    }
}

// ---- per bucket (512 threads): LDS degree+scan -> rowptr/dinv; place col ----
__global__ void k_place2(const int* __restrict__ packed, const int* __restrict__ bstart,
                         int* __restrict__ col, int* __restrict__ rp,
                         float* __restrict__ dinv, int n) {
    __shared__ int deg[BKT];
    __shared__ int sc[BKT];
    __shared__ int cur[BKT];
    int t = threadIdx.x;
    deg[t] = 0;
    __syncthreads();
    int start = bstart[blockIdx.x];
    int end = bstart[blockIdx.x + 1];
    for (int i = start + t; i < end; i += BKT)
        atomicAdd(&deg[packed[i] & (BKT - 1)], 1);
    __syncthreads();
    int d0 = deg[t];
    sc[t] = d0;
    __syncthreads();
    int val = d0;
    for (int off = 1; off < BKT; off <<= 1) {
        int other = (t >= off) ? sc[t - off] : 0;
        __syncthreads();
        val += other;
        sc[t] = val;
        __syncthreads();
    }
    int node = blockIdx.x * BKT + t;
    int ex = start + val - d0;   // bucket start + exclusive prefix
    if (node < n) {
        rp[node] = ex;
        dinv[node] = rsqrtf((float)d0 + 1.0f);
    }
    cur[t] = ex;
    __syncthreads();
    for (int i = start + t; i < end; i += BKT) {
        int u = packed[i];
        int p = atomicAdd(&cur[u & (BKT - 1)], 1);
        col[p] = u >> BKTL2;
    }
}

// ---- h0s = (x @ W1) * dinv, fp16, two planes ----
__global__ void k_xw1(const float* __restrict__ x, const float* __restrict__ W1,
                      const float* __restrict__ dinv,
                      _Float16* __restrict__ p0, _Float16* __restrict__ p1, int n) {
    int i = blockIdx.x * blockDim.x + threadIdx.x;
    if (i >= n * F) return;
    int node = i >> 5, f = i & (F - 1);
    float x0 = x[node * 3 + 0], x1 = x[node * 3 + 1], x2 = x[node * 3 + 2];
    float v = (x0 * W1[f] + x1 * W1[F + f] + x2 * W1[2 * F + f]) * dinv[node];
    _Float16* plane = (f < 16) ? p0 : p1;
    plane[node * 16 + (f & 15)] = (_Float16)v;
}

// ---- gs = (h @ W2) * dinv, fp16 planes in/out, fp32 accumulate ----
__global__ void k_gemm2(const _Float16* __restrict__ h0, const _Float16* __restrict__ h1,
                        const float* __restrict__ W2, const float* __restrict__ dinv,
                        _Float16* __restrict__ g0, _Float16* __restrict__ g1, int n) {
    int i = blockIdx.x * blockDim.x + threadIdx.x;
    if (i >= n * F) return;
    int node = i >> 5, f = i & (F - 1);
    const _Float16* r0 = h0 + (size_t)node * 16;
    const _Float16* r1 = h1 + (size_t)node * 16;
    float acc = 0.0f;
#pragma unroll
    for (int k = 0; k < 16; ++k) acc += (float)r0[k] * W2[k * F + f];
#pragma unroll
    for (int k = 0; k < 16; ++k) acc += (float)r1[k] * W2[(k + 16) * F + f];
    _Float16* plane = (f < 16) ? g0 : g1;
    plane[node * 16 + (f & 15)] = (_Float16)(acc * dinv[node]);
}

// ---- fused gather conv + bias + relu + pool; prescaled rows, no edge dinv ----
// plane = blockIdx&7 quadrant (XCD pinning); 32 nodes/block; thread t:
// nodeLocal = t>>3, rr = t&7 owns contiguous 1/8 of node's edges, full
// 16-feat plane row per edge (2 x half8 from one 32B line).
// Requires N % 32 == 0 (all lanes of a wave valid).
__global__ void k_gather3(const _Float16* __restrict__ pl0, const _Float16* __restrict__ pl1,
                          const int* __restrict__ rp, const int* __restrict__ col,
                          const float* __restrict__ dinv, const float* __restrict__ bias,
                          const int* __restrict__ batch,
                          _Float16* __restrict__ out0, _Float16* __restrict__ out1,
                          float* __restrict__ psum, float* __restrict__ pmax,
                          float* __restrict__ cnt, int n, int ne, int nPB,
                          int store, int do_cnt) {
    int grp = blockIdx.x >> 3, sub = blockIdx.x & 7;
    int plane = sub >> 2;
    int lb = grp * 4 + (sub & 3);
    if (lb >= nPB) return;
    int t = threadIdx.x;
    int node = (lb << 5) + (t >> 3);
    int rr = t & 7;
    if (node >= n) return;

    const _Float16* hin = plane ? pl1 : pl0;
    int start = rp[node];
    int end = (node + 1 < n) ? rp[node + 1] : ne;
    int len = end - start;
    int m0 = start + ((len * rr) >> 3);
    int m1 = start + ((len * (rr + 1)) >> 3);
    float dv = dinv[node];

    float acc[16];
    if (rr == 0) {   // self term: prescaled row of node itself
        half8 a = *reinterpret_cast<const half8*>(hin + (size_t)node * 16);
        half8 b = *reinterpret_cast<const half8*>(hin + (size_t)node * 16 + 8);
#pragma unroll
        for (int j = 0; j < 8; ++j) { acc[j] = (float)a[j]; acc[8 + j] = (float)b[j]; }
    } else {
#pragma unroll
        for (int j = 0; j < 16; ++j) acc[j] = 0.0f;
    }

    int e = m0;
    for (; e + 4 <= m1; e += 4) {
        int s0 = col[e], s1 = col[e + 1], s2 = col[e + 2], s3 = col[e + 3];
        half8 a0 = *reinterpret_cast<const half8*>(hin + (size_t)s0 * 16);
        half8 b0 = *reinterpret_cast<const half8*>(hin + (size_t)s0 * 16 + 8);
        half8 a1 = *reinterpret_cast<const half8*>(hin + (size_t)s1 * 16);
        half8 b1 = *reinterpret_cast<const half8*>(hin + (size_t)s1 * 16 + 8);
        half8 a2 = *reinterpret_cast<const half8*>(hin + (size_t)s2 * 16);
        half8 b2 = *reinterpret_cast<const half8*>(hin + (size_t)s2 * 16 + 8);
        half8 a3 = *reinterpret_cast<const half8*>(hin + (size_t)s3 * 16);
        half8 b3 = *reinterpret_cast<const half8*>(hin + (size_t)s3 * 16 + 8);
#pragma unroll
        for (int j = 0; j < 8; ++j) {
            acc[j]     += (float)a0[j] + (float)a1[j] + (float)a2[j] + (float)a3[j];
            acc[8 + j] += (float)b0[j] + (float)b1[j] + (float)b2[j] + (float)b3[j];
        }
    }
    for (; e < m1; ++e) {
        int s = col[e];
        half8 a = *reinterpret_cast<const half8*>(hin + (size_t)s * 16);
        half8 b = *reinterpret_cast<const half8*>(hin + (size_t)s * 16 + 8);
#pragma unroll
        for (int j = 0; j < 8; ++j) { acc[j] += (float)a[j]; acc[8 + j] += (float)b[j]; }
    }

    // combine the 8 edge-slices of this node (lanes differ in bits 0-2)
#pragma unroll
    for (int off = 1; off < 8; off <<= 1)
#pragma unroll
        for (int j = 0; j < 16; ++j) acc[j] += __shfl_xor(acc[j], off);

    float vv[16];
#pragma unroll
    for (int j = 0; j < 16; ++j)
        vv[j] = fmaxf(dv * acc[j] + bias[plane * 16 + j], 0.0f);

    if (store && rr == 0) {
        _Float16* hout = plane ? out1 : out0;
        half8 oa, ob;
#pragma unroll
        for (int j = 0; j < 8; ++j) { oa[j] = (_Float16)vv[j]; ob[j] = (_Float16)vv[8 + j]; }
        *reinterpret_cast<half8*>(hout + (size_t)node * 16) = oa;
        *reinterpret_cast<half8*>(hout + (size_t)node * 16 + 8) = ob;
    }

    int b = batch[node];
    int lane = t & 63;
    int bFirst = __shfl(b, 0);
    int bLast  = __shfl(b, 63);
    if (bFirst == bLast) {
        // 8 nodes/wave: reduce across node dim (strides 8,16,32)
        float sv[16], mv[16];
#pragma unroll
        for (int j = 0; j < 16; ++j) { sv[j] = vv[j]; mv[j] = vv[j]; }
        for (int off = 8; off < 64; off <<= 1) {
#pragma unroll
            for (int j = 0; j < 16; ++j) {
                sv[j] += __shfl_down(sv[j], off);
                mv[j] = fmaxf(mv[j], __shfl_down(mv[j], off));
            }
        }
        if (lane < 2) {   // lane 0: feats 0-7, lane 1: feats 8-15 (full copies)
            float* ps = psum + b * F + plane * 16 + lane * 8;
            int* pm = reinterpret_cast<int*>(pmax + b * F + plane * 16 + lane * 8);
#pragma unroll
            for (int j = 0; j < 8; ++j) {
                atomicAdd(ps + j, sv[lane * 8 + j]);
                atomicMax(pm + j, __float_as_int(mv[lane * 8 + j]));  // vv >= 0
            }
            if (do_cnt && plane == 0 && lane == 0) atomicAdd(&cnt[b], 8.0f);
        }
    } else if (rr == 0) {
        float* ps = psum + b * F + plane * 16;
        int* pm = reinterpret_cast<int*>(pmax + b * F + plane * 16);
#pragma unroll
        for (int j = 0; j < 16; ++j) {
            atomicAdd(ps + j, vv[j]);
            atomicMax(pm + j, __float_as_int(vv[j]));
        }
        if (do_cnt && plane == 0) atomicAdd(&cnt[b], 1.0f);
    }
}

// ---- fused MLP head: one block per graph (64 threads) ----
__global__ void k_mlp(const float* __restrict__ sum1, const float* __restrict__ max1,
                      const float* __restrict__ sum2, const float* __restrict__ max2,
                      const float* __restrict__ cnt,
                      const float* __restrict__ LW1, const float* __restrict__ Lb1,
                      const float* __restrict__ LW2, const float* __restrict__ Lb2,
                      float* __restrict__ out, int outd) {
    __shared__ float zs[POOLD];
    int b = blockIdx.x, j = threadIdx.x;  // blockDim.x == 64
    float invc = 1.0f / fmaxf(cnt[b], 1.0f);
    float acc = Lb1[j];
#pragma unroll
    for (int i = 0; i < POOLD; ++i) {
        float s;
        if (i < F) s = max1[b * F + i] + max2[b * F + i];
        else       s = (sum1[b * F + i - F] + sum2[b * F + i - F]) * invc;
        acc += s * LW1[i * POOLD + j];
    }
    zs[j] = fmaxf(acc, 0.0f);
    __syncthreads();
    if (j < outd) {
        float a2 = Lb2[j];
#pragma unroll
        for (int jj = 0; jj < POOLD; ++jj) a2 += zs[jj] * LW2[jj * outd + j];
        out[b * outd + j] = a2;
    }
}

extern "C" void kernel_launch(void* const* d_in, const int* in_sizes, int n_in,
                              void* d_out, int out_size, void* d_ws, size_t ws_size,
                              hipStream_t stream) {
    const float* x    = (const float*)d_in[0];
    const int*   ei   = (const int*)d_in[1];
    const int*   batch= (const int*)d_in[2];
    const float* W1   = (const float*)d_in[3];
    const float* b1   = (const float*)d_in[4];
    const float* W2   = (const float*)d_in[5];
    const float* b2   = (const float*)d_in[6];
    const float* LW1  = (const float*)d_in[7];
    const float* Lb1  = (const float*)d_in[8];
    const float* LW2  = (const float*)d_in[9];
    const float* Lb2  = (const float*)d_in[10];
    float* out = (float*)d_out;

    const int N = in_sizes[0] / 3;
    const int E = in_sizes[1] / 2;
    const int OUTD = in_sizes[10];
    const int B = out_size / OUTD;
    const int poolsz = 4 * B * F + B;
    const int NBUCK = (N + BKT - 1) / BKT;      // <= MAXBUCK
    const int NBLK = (E + EPB - 1) / EPB;
    const int NPB = (N + 31) / 32;              // gather blocks per plane

    // ---- workspace layout ----
    char* p = (char*)d_ws;
    float* pools= (float*)p;          p += (size_t)poolsz * 4;
    int* bcnt   = (int*)p;            p += (size_t)NBUCK * NBLK * 4;
    int* tot    = (int*)p;            p += (size_t)MAXBUCK * 4;
    int* bstart = (int*)p;            p += (size_t)(NBUCK + 1) * 4;
    int* rowptr = (int*)p;            p += (size_t)N * 4;
    int* col    = (int*)p;            p += (size_t)E * 4;
    float* dinv = (float*)p;          p += (size_t)N * 4;
    _Float16* b0p0 = (_Float16*)p;    p += (size_t)N * 16 * 2;   // buf0 plane0
    _Float16* b0p1 = (_Float16*)p;    p += (size_t)N * 16 * 2;   // buf0 plane1
    _Float16* b1p0 = (_Float16*)p;    p += (size_t)N * 16 * 2;   // buf1 plane0
    _Float16* b1p1 = (_Float16*)p;    p += (size_t)N * 16 * 2;   // buf1 plane1
    int* packed = (int*)b0p0;         // aliased over the 4 planes (E*4 == N*F*4 B);
                                      // consumed by k_place2 before planes written
    float* sum1 = pools;
    float* max1 = sum1 + B * F;
    float* sum2 = max1 + B * F;
    float* max2 = sum2 + B * F;
    float* cnt  = max2 + B * F;

    const int BS = 256;
    auto g1 = [&](long long n) { return (int)((n + BS - 1) / BS); };
    const int gatherBlocks = ((NPB + 3) / 4) * 8;

    // CSR build + norms (zero global atomics)
    hipMemsetAsync(pools, 0, (size_t)poolsz * 4, stream);
    k_histB<<<NBLK, BS, 0, stream>>>(ei, bcnt, E, NBUCK, NBLK);
    k_rowscan<<<NBUCK, 256, 0, stream>>>(bcnt, tot, NBLK);
    k_bscan<<<1, 256, 0, stream>>>(tot, bstart, NBUCK, E);
    k_bin<<<NBLK, BS, 0, stream>>>(ei, bstart, bcnt, packed, E, NBUCK, NBLK);
    k_place2<<<NBUCK, BKT, 0, stream>>>(packed, bstart, col, rowptr, dinv, N);

    // layer 1: prescaled h0 planes -> dual-plane gather -> h (buf1 planes)
    k_xw1<<<g1((long long)N * F), BS, 0, stream>>>(x, W1, dinv, b0p0, b0p1, N);
    k_gather3<<<gatherBlocks, BS, 0, stream>>>(b0p0, b0p1, rowptr, col, dinv, b1,
                                               batch, b1p0, b1p1, sum1, max1, cnt,
                                               N, E, NPB, /*store=*/1, /*cnt=*/1);
    // layer 2: prescaled g planes -> gather
    k_gemm2<<<g1((long long)N * F), BS, 0, stream>>>(b1p0, b1p1, W2, dinv,
                                                     b0p0, b0p1, N);
    k_gather3<<<gatherBlocks, BS, 0, stream>>>(b0p0, b0p1, rowptr, col, dinv, b2,
                                               batch, b1p0, b1p1, sum2, max2, cnt,
                                               N, E, NPB, /*store=*/0, /*cnt=*/0);

    // MLP head
    k_mlp<<<B, 64, 0, stream>>>(sum1, max1, sum2, max2, cnt,
                                LW1, Lb1, LW2, Lb2, out, OUTD);
}

// Round 12
// 321.237 us; speedup vs baseline: 1.4178x; 1.4178x over previous
//
#include <hip/hip_runtime.h>
#include <hip/hip_fp16.h>

// Topology encoder: 2-layer GCN (N=100k nodes, E=3.2M edges) + max/mean pool
// over B=64 graphs + 2-layer MLP. fp32 in/out; node features fp16 N x 32
// (64B rows), PRE-SCALED by dinv so the gather inner loop has NO per-edge
// dinv load:  out[d] = relu(bias + dinv[d] * (sum_{s in N(d)} hs[s] + hs[d])),
// hs[x] = h[x]*dinv[x] (scale applied at write in k_xw1 / k_gemm2).
//
// CSR-by-dst built per call with ZERO global atomics (histB/rowscan/bscan/
// bin/place2). Gather: 4 threads/node (8 feats each, no cross-lane combine),
// 8-deep unrolled edge loop. Pool atomics wave-reduced when wave is
// single-graph (batch sorted).

#define F 32
#define POOLD 64
#define BKT 512           // nodes per bucket (log2 = 9); place2 blockDim == BKT
#define BKTL2 9
#define EPB 8192          // edges per k_histB/k_bin block
#define MAXBUCK 256       // supports N <= 131072

typedef __attribute__((ext_vector_type(8))) _Float16 half8;

// ---- per-block LDS bucket histogram; direct store to bcnt[b][blk] ----
__global__ void k_histB(const int* __restrict__ ei, int* __restrict__ bcnt,
                        int e, int nbuck, int nblk) {
    __shared__ int h[MAXBUCK];
    for (int b = threadIdx.x; b < nbuck; b += 256) h[b] = 0;
    __syncthreads();
    int base = blockIdx.x * EPB;
#pragma unroll
    for (int k = 0; k < EPB / 1024; ++k) {
        int i = base + (k * 256 + threadIdx.x) * 4;
        if (i + 4 <= e) {
            int4 d4 = *reinterpret_cast<const int4*>(ei + e + i);
            atomicAdd(&h[d4.x >> BKTL2], 1);
            atomicAdd(&h[d4.y >> BKTL2], 1);
            atomicAdd(&h[d4.z >> BKTL2], 1);
            atomicAdd(&h[d4.w >> BKTL2], 1);
        } else {
            for (int j = i; j < e && j < i + 4; ++j)
                atomicAdd(&h[ei[e + j] >> BKTL2], 1);
        }
    }
    __syncthreads();
    for (int b = threadIdx.x; b < nbuck; b += 256)
        bcnt[b * nblk + blockIdx.x] = h[b];
}

// ---- per bucket: exclusive scan of bcnt row (in place) + row total ----
__global__ void k_rowscan(int* __restrict__ bcnt, int* __restrict__ tot, int nblk) {
    __shared__ int lds[256];
    int* row = bcnt + (size_t)blockIdx.x * nblk;
    int t = threadIdx.x;
    int running = 0;
    for (int chunk = 0; chunk < nblk; chunk += 256) {
        int idx = chunk + t;
        int v = (idx < nblk) ? row[idx] : 0;
        lds[t] = v;
        __syncthreads();
        int val = v;
        for (int off = 1; off < 256; off <<= 1) {
            int other = (t >= off) ? lds[t - off] : 0;
            __syncthreads();
            val += other;
            lds[t] = val;
            __syncthreads();
        }
        if (idx < nblk) row[idx] = running + val - v;  // exclusive
        running += lds[255];
        __syncthreads();
    }
    if (t == 0) tot[blockIdx.x] = running;
}

// ---- single block: scan bucket totals -> bstart (nbuck <= 256) ----
__global__ void k_bscan(const int* __restrict__ tot, int* __restrict__ bstart,
                        int nbuck, int e) {
    __shared__ int lds[256];
    int t = threadIdx.x;
    int v = (t < nbuck) ? tot[t] : 0;
    lds[t] = v;
    __syncthreads();
    int val = v;
    for (int off = 1; off < 256; off <<= 1) {
        int other = (t >= off) ? lds[t - off] : 0;
        __syncthreads();
        val += other;
        lds[t] = val;
        __syncthreads();
    }
    if (t < nbuck) bstart[t] = val - v;  // exclusive
    if (t == 0) bstart[nbuck] = e;
}

// ---- partition edges into private per-(bucket,block) runs; LDS cursors ----
__global__ void k_bin(const int* __restrict__ ei, const int* __restrict__ bstart,
                      const int* __restrict__ bcnt, int* __restrict__ packed,
                      int e, int nbuck, int nblk) {
    __shared__ int cur[MAXBUCK];
    for (int b = threadIdx.x; b < nbuck; b += 256)
        cur[b] = bstart[b] + bcnt[b * nblk + blockIdx.x];
    __syncthreads();
    int base = blockIdx.x * EPB;
#pragma unroll
    for (int k = 0; k < EPB / 1024; ++k) {
        int i = base + (k * 256 + threadIdx.x) * 4;
        if (i + 4 <= e) {
            int4 s4 = *reinterpret_cast<const int4*>(ei + i);
            int4 d4 = *reinterpret_cast<const int4*>(ei + e + i);
            int p0 = atomicAdd(&cur[d4.x >> BKTL2], 1);
            int p1 = atomicAdd(&cur[d4.y >> BKTL2], 1);
            int p2 = atomicAdd(&cur[d4.z >> BKTL2], 1);
            int p3 = atomicAdd(&cur[d4.w >> BKTL2], 1);
            packed[p0] = (s4.x << BKTL2) | (d4.x & (BKT - 1));
            packed[p1] = (s4.y << BKTL2) | (d4.y & (BKT - 1));
            packed[p2] = (s4.z << BKTL2) | (d4.z & (BKT - 1));
            packed[p3] = (s4.w << BKTL2) | (d4.w & (BKT - 1));
        } else {
            for (int j = i; j < e && j < i + 4; ++j) {
                int s = ei[j], d = ei[e + j];
                int p = atomicAdd(&cur[d >> BKTL2], 1);
                packed[p] = (s << BKTL2) | (d & (BKT - 1));
            }
        }
    }
}

// ---- per bucket (512 threads): LDS degree+scan -> rowptr/dinv; place col ----
__global__ void k_place2(const int* __restrict__ packed, const int* __restrict__ bstart,
                         int* __restrict__ col, int* __restrict__ rp,
                         float* __restrict__ dinv, int n) {
    __shared__ int deg[BKT];
    __shared__ int sc[BKT];
    __shared__ int cur[BKT];
    int t = threadIdx.x;
    deg[t] = 0;
    __syncthreads();
    int start = bstart[blockIdx.x];
    int end = bstart[blockIdx.x + 1];
    for (int i = start + t; i < end; i += BKT)
        atomicAdd(&deg[packed[i] & (BKT - 1)], 1);
    __syncthreads();
    int d0 = deg[t];
    sc[t] = d0;
    __syncthreads();
    int val = d0;
    for (int off = 1; off < BKT; off <<= 1) {
        int other = (t >= off) ? sc[t - off] : 0;
        __syncthreads();
        val += other;
        sc[t] = val;
        __syncthreads();
    }
    int node = blockIdx.x * BKT + t;
    int ex = start + val - d0;   // bucket start + exclusive prefix
    if (node < n) {
        rp[node] = ex;
        dinv[node] = rsqrtf((float)d0 + 1.0f);
    }
    cur[t] = ex;
    __syncthreads();
    for (int i = start + t; i < end; i += BKT) {
        int u = packed[i];
        int p = atomicAdd(&cur[u & (BKT - 1)], 1);
        col[p] = u >> BKTL2;
    }
}

// ---- h0s = (x @ W1) * dinv, fp16 N x 32 ----
__global__ void k_xw1(const float* __restrict__ x, const float* __restrict__ W1,
                      const float* __restrict__ dinv,
                      _Float16* __restrict__ h0, int n) {
    int i = blockIdx.x * blockDim.x + threadIdx.x;
    if (i >= n * F) return;
    int node = i >> 5, f = i & (F - 1);
    float x0 = x[node * 3 + 0], x1 = x[node * 3 + 1], x2 = x[node * 3 + 2];
    h0[i] = (_Float16)((x0 * W1[f] + x1 * W1[F + f] + x2 * W1[2 * F + f]) * dinv[node]);
}

// ---- gs = (h @ W2) * dinv, fp16 in/out, fp32 accumulate ----
__global__ void k_gemm2(const _Float16* __restrict__ h, const float* __restrict__ W2,
                        const float* __restrict__ dinv,
                        _Float16* __restrict__ g, int n) {
    int i = blockIdx.x * blockDim.x + threadIdx.x;
    if (i >= n * F) return;
    int node = i >> 5, f = i & (F - 1);
    const _Float16* row = h + (size_t)node * F;
    float acc = 0.0f;
#pragma unroll
    for (int k = 0; k < F; ++k) acc += (float)row[k] * W2[k * F + f];
    g[i] = (_Float16)(acc * dinv[node]);
}

// ---- fused gather conv + bias + relu + pool; prescaled rows ----
// 4 threads/node (q = t&3 owns 8 feats); per edge: 1 col + 1 16B row load.
// 8-deep unrolled edge loop = 8 independent row loads in flight.
__global__ void k_gather(const _Float16* __restrict__ hin, const int* __restrict__ rp,
                         const int* __restrict__ col, const float* __restrict__ dinv,
                         const float* __restrict__ bias, const int* __restrict__ batch,
                         _Float16* __restrict__ hout,
                         float* __restrict__ psum, float* __restrict__ pmax,
                         float* __restrict__ cnt, int n, int ne, int store, int do_cnt) {
    int t = blockIdx.x * blockDim.x + threadIdx.x;
    int node = t >> 2, q = t & 3;
    if (node >= n) return;
    int start = rp[node];
    int end = (node + 1 < n) ? rp[node + 1] : ne;
    float dv = dinv[node];

    // self term: hs[node] (prescaled) joins the sum directly
    half8 hv = *reinterpret_cast<const half8*>(hin + (size_t)node * F + q * 8);
    float acc[8];
#pragma unroll
    for (int j = 0; j < 8; ++j) acc[j] = (float)hv[j];

    int e = start;
    for (; e + 8 <= end; e += 8) {
        int s[8];
#pragma unroll
        for (int u = 0; u < 8; ++u) s[u] = col[e + u];
        half8 v[8];
#pragma unroll
        for (int u = 0; u < 8; ++u)
            v[u] = *reinterpret_cast<const half8*>(hin + (size_t)s[u] * F + q * 8);
#pragma unroll
        for (int u = 0; u < 8; ++u)
#pragma unroll
            for (int j = 0; j < 8; ++j) acc[j] += (float)v[u][j];
    }
    for (; e < end; ++e) {
        int s = col[e];
        half8 v = *reinterpret_cast<const half8*>(hin + (size_t)s * F + q * 8);
#pragma unroll
        for (int j = 0; j < 8; ++j) acc[j] += (float)v[j];
    }

    float vv[8];
#pragma unroll
    for (int j = 0; j < 8; ++j)
        vv[j] = fmaxf(dv * acc[j] + bias[q * 8 + j], 0.0f);
    if (store) {
        half8 o;
#pragma unroll
        for (int j = 0; j < 8; ++j) o[j] = (_Float16)vv[j];
        *reinterpret_cast<half8*>(hout + (size_t)node * F + q * 8) = o;
    }

    int b = batch[node];
    int lane = threadIdx.x & 63;
    int bFirst = __shfl(b, 0);
    int bLast  = __shfl(b, 63);
    if (bFirst == bLast) {
        // 16 nodes per wave: tree-reduce across node dim (strides 4,8,16,32)
        float sv[8], mv[8];
#pragma unroll
        for (int j = 0; j < 8; ++j) { sv[j] = vv[j]; mv[j] = vv[j]; }
        for (int off = 4; off < 64; off <<= 1) {
#pragma unroll
            for (int j = 0; j < 8; ++j) {
                sv[j] += __shfl_down(sv[j], off);
                mv[j] = fmaxf(mv[j], __shfl_down(mv[j], off));
            }
        }
        if (lane < 4) {
            float* ps = psum + b * F + lane * 8;
            int* pm = reinterpret_cast<int*>(pmax + b * F + lane * 8);
#pragma unroll
            for (int j = 0; j < 8; ++j) {
                atomicAdd(ps + j, sv[j]);
                atomicMax(pm + j, __float_as_int(mv[j]));  // vv >= 0
            }
            if (do_cnt && lane == 0) atomicAdd(&cnt[b], 16.0f);
        }
    } else {
        float* ps = psum + b * F + q * 8;
        int* pm = reinterpret_cast<int*>(pmax + b * F + q * 8);
#pragma unroll
        for (int j = 0; j < 8; ++j) {
            atomicAdd(ps + j, vv[j]);
            atomicMax(pm + j, __float_as_int(vv[j]));
        }
        if (do_cnt && q == 0) atomicAdd(&cnt[b], 1.0f);
    }
}

// ---- fused MLP head: one block per graph (64 threads) ----
__global__ void k_mlp(const float* __restrict__ sum1, const float* __restrict__ max1,
                      const float* __restrict__ sum2, const float* __restrict__ max2,
                      const float* __restrict__ cnt,
                      const float* __restrict__ LW1, const float* __restrict__ Lb1,
                      const float* __restrict__ LW2, const float* __restrict__ Lb2,
                      float* __restrict__ out, int outd) {
    __shared__ float zs[POOLD];
    int b = blockIdx.x, j = threadIdx.x;  // blockDim.x == 64
    float invc = 1.0f / fmaxf(cnt[b], 1.0f);
    float acc = Lb1[j];
#pragma unroll
    for (int i = 0; i < POOLD; ++i) {
        float s;
        if (i < F) s = max1[b * F + i] + max2[b * F + i];
        else       s = (sum1[b * F + i - F] + sum2[b * F + i - F]) * invc;
        acc += s * LW1[i * POOLD + j];
    }
    zs[j] = fmaxf(acc, 0.0f);
    __syncthreads();
    if (j < outd) {
        float a2 = Lb2[j];
#pragma unroll
        for (int jj = 0; jj < POOLD; ++jj) a2 += zs[jj] * LW2[jj * outd + j];
        out[b * outd + j] = a2;
    }
}

extern "C" void kernel_launch(void* const* d_in, const int* in_sizes, int n_in,
                              void* d_out, int out_size, void* d_ws, size_t ws_size,
                              hipStream_t stream) {
    const float* x    = (const float*)d_in[0];
    const int*   ei   = (const int*)d_in[1];
    const int*   batch= (const int*)d_in[2];
    const float* W1   = (const float*)d_in[3];
    const float* b1   = (const float*)d_in[4];
    const float* W2   = (const float*)d_in[5];
    const float* b2   = (const float*)d_in[6];
    const float* LW1  = (const float*)d_in[7];
    const float* Lb1  = (const float*)d_in[8];
    const float* LW2  = (const float*)d_in[9];
    const float* Lb2  = (const float*)d_in[10];
    float* out = (float*)d_out;

    const int N = in_sizes[0] / 3;
    const int E = in_sizes[1] / 2;
    const int OUTD = in_sizes[10];
    const int B = out_size / OUTD;
    const int poolsz = 4 * B * F + B;
    const int NBUCK = (N + BKT - 1) / BKT;      // <= MAXBUCK
    const int NBLK = (E + EPB - 1) / EPB;

    // ---- workspace layout ----
    char* p = (char*)d_ws;
    float* pools= (float*)p;          p += (size_t)poolsz * 4;
    int* bcnt   = (int*)p;            p += (size_t)NBUCK * NBLK * 4;
    int* tot    = (int*)p;            p += (size_t)MAXBUCK * 4;
    int* bstart = (int*)p;            p += (size_t)(NBUCK + 1) * 4;
    int* rowptr = (int*)p;            p += (size_t)N * 4;
    int* col    = (int*)p;            p += (size_t)E * 4;
    float* dinv = (float*)p;          p += (size_t)N * 4;
    _Float16* buf0 = (_Float16*)p;    p += (size_t)N * F * 2;
    _Float16* buf1 = (_Float16*)p;    p += (size_t)N * F * 2;
    int* packed = (int*)buf0;         // aliased over buf0+buf1 (E*4 == N*F*4 B);
                                      // consumed by k_place2 before bufs written
    float* sum1 = pools;
    float* max1 = sum1 + B * F;
    float* sum2 = max1 + B * F;
    float* max2 = sum2 + B * F;
    float* cnt  = max2 + B * F;

    const int BS = 256;
    auto g1 = [&](long long n) { return (int)((n + BS - 1) / BS); };

    // CSR build + norms (zero global atomics)
    hipMemsetAsync(pools, 0, (size_t)poolsz * 4, stream);
    k_histB<<<NBLK, BS, 0, stream>>>(ei, bcnt, E, NBUCK, NBLK);
    k_rowscan<<<NBUCK, 256, 0, stream>>>(bcnt, tot, NBLK);
    k_bscan<<<1, 256, 0, stream>>>(tot, bstart, NBUCK, E);
    k_bin<<<NBLK, BS, 0, stream>>>(ei, bstart, bcnt, packed, E, NBUCK, NBLK);
    k_place2<<<NBUCK, BKT, 0, stream>>>(packed, bstart, col, rowptr, dinv, N);

    // layer 1: prescaled h0 -> gather -> h (buf1)
    k_xw1<<<g1((long long)N * F), BS, 0, stream>>>(x, W1, dinv, buf0, N);
    k_gather<<<g1((long long)N * 4), BS, 0, stream>>>(buf0, rowptr, col, dinv, b1,
                                                      batch, buf1, sum1, max1, cnt,
                                                      N, E, /*store=*/1, /*cnt=*/1);
    // layer 2: prescaled g -> gather
    k_gemm2<<<g1((long long)N * F), BS, 0, stream>>>(buf1, W2, dinv, buf0, N);
    k_gather<<<g1((long long)N * 4), BS, 0, stream>>>(buf0, rowptr, col, dinv, b2,
                                                      batch, buf1, sum2, max2, cnt,
                                                      N, E, /*store=*/0, /*cnt=*/0);

    // MLP head
    k_mlp<<<B, 64, 0, stream>>>(sum1, max1, sum2, max2, cnt,
                                LW1, Lb1, LW2, Lb2, out, OUTD);
}